// Round 14
// baseline (588.002 us; speedup 1.0000x reference)
//
#include <hip/hip_runtime.h>
#include <hip/hip_bf16.h>

// BMMGroupedGEMM: out[e,m,n] = sum_k x[e,m,k] * w[e,n,k], rows m >= m_sizes[e] zeroed.
// E=8, MAX_M=2048, K=2048, N=8192. fp32 in/out.
// Round 14: TWO independent barrier domains per CU. Tile 128x256, 4 waves,
// 256 threads, BK=32, 3-deep LDS ring (72 KB) -> 2 blocks/CU. Same 8 waves/CU
// as R6-R13, but when one block stalls at its vmcnt+barrier the OTHER block's
// waves keep issuing MFMA (m114 cross-block overlap -- the one structural
// element every 1-block/CU design R4-R13 lacked; single barrier domain = whole
// CU stalls together, the invariant ~1100cyc/phase gap).
// Phase (K-tile t, ring cur): {stage t+2 -> (cur+2)%3 | 12 ds_read | BAR |
//   setprio 32 MFMA | vmcnt(6) | BAR}. Ledger: enter 6 {t+1}; +6 {t+2} -> 12;
//   vmcnt(6) drains t+1 (read next phase). WAR: ring (cur+2)%3 last read at
//   phase t-1, >=2 barriers before writes land. Tail: stg=false -> vmcnt(0).
// Swizzle, expert-major balanced work list, persistent virtual-K ring, merged
// cvt dispatch all carried over unchanged from R13 (best measured: 581 us).

#define NE   8
#define MAXM 2048
#define KD   2048
#define ND   8192

#define BM   128
#define BN   256
#define BK   32
#define NTS  (KD/BK)     // 64 K-tiles per output tile

typedef __attribute__((ext_vector_type(8))) short          short8;
typedef __attribute__((ext_vector_type(8))) unsigned short us8;
typedef __attribute__((ext_vector_type(4))) float          f32x4;
typedef __attribute__((ext_vector_type(4))) unsigned short us4;

__device__ __forceinline__ unsigned short f2bf(float f) {
    union { float f; unsigned u; } v; v.f = f;
    unsigned u = v.u;
    return (unsigned short)((u + 0x7FFFu + ((u >> 16) & 1u)) >> 16);  // RNE
}

__device__ __forceinline__ void gload16(const void* g, void* l) {
    __builtin_amdgcn_global_load_lds(
        (const __attribute__((address_space(1))) void*)g,
        (__attribute__((address_space(3))) void*)l, 16, 0, 0);
}

// ---------------- Pass 1: merged fp32->bf16 conversion (X masked rows skipped) ------
__global__ __launch_bounds__(256) void cvt_all_kernel(const float* __restrict__ x,
                                                      const float* __restrict__ w,
                                                      unsigned short* __restrict__ xb,
                                                      unsigned short* __restrict__ wb,
                                                      const int* __restrict__ ms) {
    int b = blockIdx.x;
    int t = threadIdx.x;
    if (b < NE * MAXM) {
        int e = b >> 11, m = b & 2047;
        if (m >= ms[e]) return;
        const float* s = x + ((size_t)e * MAXM + m) * KD;
        unsigned short* d = xb + ((size_t)e * MAXM + m) * KD;
        const f32x4* s4 = (const f32x4*)(s + t * 8);
        f32x4 a = s4[0], bb = s4[1];
        us8 v = (us8){f2bf(a[0]), f2bf(a[1]), f2bf(a[2]), f2bf(a[3]),
                      f2bf(bb[0]), f2bf(bb[1]), f2bf(bb[2]), f2bf(bb[3])};
        *(us8*)(d + t * 8) = v;
    } else {
        const int nW8 = (int)(((size_t)NE * ND * KD) / 8);   // 16,777,216
        int i = (b - NE * MAXM) * 256 + t;
        int stride = 2048 * 256;
        for (; i < nW8; i += stride) {
            const f32x4* s = (const f32x4*)(w + (size_t)i * 8);
            f32x4 a = s[0], bb = s[1];
            us8 v = (us8){f2bf(a[0]), f2bf(a[1]), f2bf(a[2]), f2bf(a[3]),
                          f2bf(bb[0]), f2bf(bb[1]), f2bf(bb[2]), f2bf(bb[3])};
            *(us8*)(wb + (size_t)i * 8) = v;
        }
    }
}

// ---------------- Pass 2: persistent 128x256 GEMM, 3-ring, 2 blocks/CU --------------
// LDS ring: Ak[3][128*32] bf16 (8KB each), Bk[3][256*32] bf16 (16KB each) = 72 KB.
// Rows are 32 bf16 = 64B = 4x16B slots. Read slot = kg ^ ((row>>1)&3); write side
// via pre-swizzled GLOBAL source (involution ss) on lane-linear gload_lds dest.
__global__ __launch_bounds__(256, 2) void ggemm_pers(
    const unsigned short* __restrict__ xb,  // [E][MAXM][KD] bf16
    const unsigned short* __restrict__ wb,  // [E][ND][KD]  bf16
    const int*   __restrict__ ms,
    float*       __restrict__ out)          // [E][MAXM][ND] fp32
{
    int p   = blockIdx.x;          // 512 blocks, 2 per CU
    int xcd = p & 7;               // HW round-robins consecutive blockIdx over XCDs
    int jj  = p >> 3;              // 0..63 within XCD
    int tid = threadIdx.x;

    __shared__ int s_live[8], s_dead[8], s_cnt[2];
    __shared__ unsigned short Ak[3][BM * 32];   // 24 KB
    __shared__ unsigned short Bk[3][BN * 32];   // 48 KB

    // Per-XCD work list, expert-major, br-major (16 rows now), 4 local bc columns.
    // Block jj takes items jj, jj+64, ... -> balanced; expert-window aligned.
    if (tid == 0) {
        int nl = 0, nd = 0, cumL = 0, cumD = 0, il = jj, id = jj;
        #pragma unroll
        for (int e = 0; e < NE; ++e) {
            int L = (ms[e] + 127) >> 7;            // live br rows, 0..16
            int cntL = L << 2, cntD = (16 - L) << 2;
            while (il < cumL + cntL) { int o = il - cumL; s_live[nl++] = (e << 6) | ((o >> 2) << 2) | (o & 3); il += 64; }
            while (id < cumD + cntD) { int o = id - cumD; s_dead[nd++] = (e << 6) | (((L + (o >> 2))) << 2) | (o & 3); id += 64; }
            cumL += cntL; cumD += cntD;
        }
        s_cnt[0] = nl; s_cnt[1] = nd;
    }
    __syncthreads();

    // zero-fill dead tiles (128x256 fp32 each)
    int ndead = s_cnt[1];
    #pragma unroll 1
    for (int d = 0; d < ndead; ++d) {
        int v = s_dead[d]; int e = v >> 6, br = (v >> 2) & 15, bcl = v & 3;
        float* outE = out + (size_t)e * MAXM * ND;
        int row0 = br * BM, col0 = (xcd * 4 + bcl) * BN;
        f32x4 z = (f32x4){0.f, 0.f, 0.f, 0.f};
        #pragma unroll
        for (int q = 0; q < 32; ++q) {
            int i2 = tid + q * 256;            // 8192 f32x4, 64 per row
            int rr = i2 >> 6, cc = (i2 & 63) << 2;
            *(f32x4*)(outE + (size_t)(row0 + rr) * ND + col0 + cc) = z;
        }
    }
    int nlive = s_cnt[0];
    if (nlive == 0) return;

    int wid = tid >> 6, lane = tid & 63;        // 4 waves, 1x4: wave owns 128 x 64
    int wc = wid;
    int lr = lane & 15, kg = lane >> 4;
    int srow = lane >> 2;
    int ss   = (lane & 3) ^ ((lane >> 3) & 3);  // pre-swizzled source slot (involution)

    auto stageA = [&](int r, const unsigned short* xP, int kt) {
        #pragma unroll
        for (int q = 0; q < 2; ++q) {
            int blk = wid * 2 + q;               // 8 chunks of 1KB (16 rows x 64B)
            const unsigned short* src =
                xP + (size_t)(blk * 16 + srow) * KD + kt * BK + ss * 8;
            gload16(src, (char*)&Ak[r][0] + blk * 1024);
        }
    };
    auto stageB = [&](int r, const unsigned short* wP, int kt) {
        #pragma unroll
        for (int q = 0; q < 4; ++q) {
            int blk = wid * 4 + q;               // 16 chunks of 1KB
            const unsigned short* src =
                wP + (size_t)(blk * 16 + srow) * KD + kt * BK + ss * 8;
            gload16(src, (char*)&Bk[r][0] + blk * 1024);
        }
    };
    auto ldA = [&](short8* a, int r) {
        #pragma unroll
        for (int mf = 0; mf < 8; ++mf) {
            int row  = mf * 16 + lr;
            int slot = kg ^ ((row >> 1) & 3);
            a[mf] = *(const short8*)&Ak[r][row * 32 + slot * 8];
        }
    };
    auto ldB4 = [&](short8* bf, int r) {
        #pragma unroll
        for (int i = 0; i < 4; ++i) {
            int row  = wc * 64 + i * 16 + lr;
            int slot = kg ^ ((row >> 1) & 3);
            bf[i] = *(const short8*)&Bk[r][row * 32 + slot * 8];
        }
    };

    f32x4 acc[8][4];
    #pragma unroll
    for (int mf = 0; mf < 8; ++mf)
        #pragma unroll
        for (int nf = 0; nf < 4; ++nf)
            acc[mf][nf] = (f32x4){0.f, 0.f, 0.f, 0.f};

    // slot metadata (cur / next)
    const unsigned short *xC, *wC, *xN, *wN;
    float *oC, *oN;
    int msC, r0C, c0C, msN, r0N, c0N;
    {
        int v = s_live[0]; int e = v >> 6, br = (v >> 2) & 15, bcl = v & 3;
        r0C = br * BM; c0C = (xcd * 4 + bcl) * BN; msC = ms[e];
        xC = xb + ((size_t)e * MAXM + r0C) * KD;
        wC = wb + ((size_t)e * ND + c0C) * KD;
        oC = out + (size_t)e * MAXM * ND;
    }
    if (nlive > 1) {
        int v = s_live[1]; int e = v >> 6, br = (v >> 2) & 15, bcl = v & 3;
        r0N = br * BM; c0N = (xcd * 4 + bcl) * BN; msN = ms[e];
        xN = xb + ((size_t)e * MAXM + r0N) * KD;
        wN = wb + ((size_t)e * ND + c0N) * KD;
        oN = out + (size_t)e * MAXM * ND;
    } else { xN = xC; wN = wC; oN = oC; msN = msC; r0N = r0C; c0N = c0C; }

    // prologue: stage t0 -> ring0, t1 -> ring1 (12 loads/wave); drain t0 (leave t1's 6).
    stageA(0, xC, 0); stageB(0, wC, 0);
    stageA(1, xC, 1); stageB(1, wC, 1);
    asm volatile("s_waitcnt vmcnt(6)" ::: "memory");
    __builtin_amdgcn_s_barrier();

    int cur = 0;   // ring index of the K-tile being computed (continuous across slots)

    #pragma unroll 1
    for (int s = 0; s < nlive; ++s) {
        bool last = (s + 1 >= nlive);

        #pragma unroll 1
        for (int kt = 0; kt < NTS; ++kt) {
            bool stg = (kt + 2 < NTS) || (!last);
            const unsigned short* xS = (kt + 2 < NTS) ? xC : xN;
            const unsigned short* wS = (kt + 2 < NTS) ? wC : wN;
            int k2 = (kt + 2 < NTS) ? kt + 2 : kt + 2 - NTS;
            int rs = (cur >= 1) ? cur - 1 : 2;   // (cur+2)%3

            if (stg) { stageA(rs, xS, k2); stageB(rs, wS, k2); }
            short8 a[8], bf[4];
            ldB4(bf, cur); ldA(a, cur);
            __builtin_amdgcn_s_barrier();
            __builtin_amdgcn_s_setprio(1);
            #pragma unroll
            for (int mf = 0; mf < 8; ++mf)
                #pragma unroll
                for (int nf = 0; nf < 4; ++nf)
                    acc[mf][nf] = __builtin_amdgcn_mfma_f32_16x16x32_bf16(a[mf], bf[nf], acc[mf][nf], 0, 0, 0);
            __builtin_amdgcn_s_setprio(0);
            if (stg) { asm volatile("s_waitcnt vmcnt(6)" ::: "memory"); }
            else     { asm volatile("s_waitcnt vmcnt(0)" ::: "memory"); }
            __builtin_amdgcn_s_barrier();
            cur = (cur + 1 == 3) ? 0 : cur + 1;
        }

        // epilogue for this slot (overlaps already-issued next-slot prefetch)
        #pragma unroll
        for (int mf = 0; mf < 8; ++mf) {
            int rbase = r0C + mf * 16 + kg * 4;
            #pragma unroll
            for (int nf = 0; nf < 4; ++nf) {
                int gc = c0C + wc * 64 + nf * 16 + lr;
                #pragma unroll
                for (int q = 0; q < 4; ++q) {
                    int gr = rbase + q;
                    float v = (gr < msC) ? acc[mf][nf][q] : 0.f;
                    oC[(size_t)gr * ND + gc] = v;
                    acc[mf][nf][q] = 0.f;
                }
            }
        }

        // shift slot window
        xC = xN; wC = wN; oC = oN; msC = msN; r0C = r0N; c0C = c0N;
        if (s + 2 < nlive) {
            int v = s_live[s + 2]; int e = v >> 6, br = (v >> 2) & 15, bcl = v & 3;
            r0N = br * BM; c0N = (xcd * 4 + bcl) * BN; msN = ms[e];
            xN = xb + ((size_t)e * MAXM + r0N) * KD;
            wN = wb + ((size_t)e * ND + c0N) * KD;
            oN = out + (size_t)e * MAXM * ND;
        }
    }
}

// ---------------- Fallback: round-1 fused kernel (used only if ws too small) --------
#define FBM 128
#define FBK 32
#define FTM (MAXM/FBM)
#define FTN (ND/FBM)
#define FNT (KD/FBK)
#define LSTR 40
__global__ __launch_bounds__(256, 2) void ggemm_fused(
    const float* __restrict__ x, const float* __restrict__ w,
    const int* __restrict__ ms, float* __restrict__ out)
{
    int nwg  = gridDim.x;
    int orig = blockIdx.x;
    int cpx  = nwg >> 3;
    int bid  = (orig & 7) * cpx + (orig >> 3);
    int e   = bid / (FTM * FTN);
    int rem = bid % (FTM * FTN);
    int br  = rem % FTM;
    int bc  = rem / FTM;
    int m_size = ms[e];
    int row0 = br * FBM, col0 = bc * FBM;
    float* outE = out + (size_t)e * MAXM * ND;
    int tid = threadIdx.x;

    if (row0 >= m_size) {
        f32x4 z = (f32x4){0.f, 0.f, 0.f, 0.f};
        #pragma unroll
        for (int q = 0; q < 16; ++q) {
            int i2 = tid + q * 256;
            int rr = i2 >> 5, cc = (i2 & 31) << 2;
            *(f32x4*)(outE + (size_t)(row0 + rr) * ND + col0 + cc) = z;
        }
        return;
    }

    const float* xE = x + ((size_t)e * MAXM + row0) * KD;
    const float* wE = w + ((size_t)e * ND   + col0) * KD;

    __shared__ unsigned short As[2][FBM][LSTR];
    __shared__ unsigned short Bs[2][FBM][LSTR];

    int sr  = tid >> 3;
    int sc4 = tid & 7;
    int wid = tid >> 6, lane = tid & 63;
    int wr = wid >> 1, wc = wid & 1;
    int lr = lane & 15, kg = lane >> 4;

    f32x4 acc[4][4];
    #pragma unroll
    for (int m = 0; m < 4; ++m)
        #pragma unroll
        for (int n = 0; n < 4; ++n)
            acc[m][n] = (f32x4){0.f, 0.f, 0.f, 0.f};

    {
        #pragma unroll
        for (int q = 0; q < 4; ++q) {
            int r0 = sr + q * 32;
            f32x4 av = *(const f32x4*)(xE + (size_t)r0 * KD + sc4 * 4);
            f32x4 bv = *(const f32x4*)(wE + (size_t)r0 * KD + sc4 * 4);
            us4 ah = (us4){f2bf(av[0]), f2bf(av[1]), f2bf(av[2]), f2bf(av[3])};
            us4 bh = (us4){f2bf(bv[0]), f2bf(bv[1]), f2bf(bv[2]), f2bf(bv[3])};
            *(us4*)&As[0][r0][sc4 * 4] = ah;
            *(us4*)&Bs[0][r0][sc4 * 4] = bh;
        }
    }
    __syncthreads();

    for (int t = 0; t < FNT; ++t) {
        int cur = t & 1;
        f32x4 av[4], bv[4];
        bool pre = (t + 1 < FNT);
        if (pre) {
            const float* xk = xE + (size_t)(t + 1) * FBK;
            const float* wk = wE + (size_t)(t + 1) * FBK;
            #pragma unroll
            for (int q = 0; q < 4; ++q) {
                int r0 = sr + q * 32;
                av[q] = *(const f32x4*)(xk + (size_t)r0 * KD + sc4 * 4);
                bv[q] = *(const f32x4*)(wk + (size_t)r0 * KD + sc4 * 4);
            }
        }
        short8 a[4], b[4];
        #pragma unroll
        for (int m = 0; m < 4; ++m)
            a[m] = *(const short8*)&As[cur][wr * 64 + m * 16 + lr][kg * 8];
        #pragma unroll
        for (int n = 0; n < 4; ++n)
            b[n] = *(const short8*)&Bs[cur][wc * 64 + n * 16 + lr][kg * 8];
        #pragma unroll
        for (int m = 0; m < 4; ++m)
            #pragma unroll
            for (int n = 0; n < 4; ++n)
                acc[m][n] = __builtin_amdgcn_mfma_f32_16x16x32_bf16(a[m], b[n], acc[m][n], 0, 0, 0);

        if (pre) {
            int nb = cur ^ 1;
            #pragma unroll
            for (int q = 0; q < 4; ++q) {
                int r0 = sr + q * 32;
                us4 ah = (us4){f2bf(av[q][0]), f2bf(av[q][1]), f2bf(av[q][2]), f2bf(av[q][3])};
                us4 bh = (us4){f2bf(bv[q][0]), f2bf(bv[q][1]), f2bf(bv[q][2]), f2bf(bv[q][3])};
                *(us4*)&As[nb][r0][sc4 * 4] = ah;
                *(us4*)&Bs[nb][r0][sc4 * 4] = bh;
            }
        }
        __syncthreads();
    }

    #pragma unroll
    for (int m = 0; m < 4; ++m) {
        int rbase = row0 + wr * 64 + m * 16 + kg * 4;
        #pragma unroll
        for (int n = 0; n < 4; ++n) {
            int gc = col0 + wc * 64 + n * 16 + lr;
            #pragma unroll
            for (int q = 0; q < 4; ++q) {
                int gr = rbase + q;
                float v = (gr < m_size) ? acc[m][n][q] : 0.f;
                outE[(size_t)gr * ND + gc] = v;
            }
        }
    }
}

extern "C" void kernel_launch(void* const* d_in, const int* in_sizes, int n_in,
                              void* d_out, int out_size, void* d_ws, size_t ws_size,
                              hipStream_t stream) {
    const float* x  = (const float*)d_in[0];
    const float* w  = (const float*)d_in[1];
    const int*   ms = (const int*)d_in[2];
    float* out = (float*)d_out;

    const size_t xElems = (size_t)NE * MAXM * KD;   // 33,554,432
    const size_t wElems = (size_t)NE * ND   * KD;   // 134,217,728
    const size_t need   = (xElems + wElems) * 2;    // 335,544,320 B

    if (ws_size >= need) {
        unsigned short* xb = (unsigned short*)d_ws;
        unsigned short* wb = xb + xElems;
        cvt_all_kernel<<<NE * MAXM + 2048, 256, 0, stream>>>(x, w, xb, wb, ms);
        ggemm_pers<<<512, 256, 0, stream>>>(xb, wb, ms, out);
    } else {
        ggemm_fused<<<dim3(NE * (MAXM/FBM) * (ND/FBM)), dim3(256), 0, stream>>>(x, w, ms, out);
    }
}

// Round 15
// 579.409 us; speedup vs baseline: 1.0148x; 1.0148x over previous
//
#include <hip/hip_runtime.h>
#include <hip/hip_bf16.h>

// BMMGroupedGEMM: out[e,m,n] = sum_k x[e,m,k] * w[e,n,k], rows m >= m_sizes[e] zeroed.
// E=8, MAX_M=2048, K=2048, N=8192. fp32 in/out.
// Round 15: R13 config (best measured, 581us; GEMM 421us x5) with ONE local change:
// 16x16x32 -> 32x32x16 MFMA (measured ubench 2382 vs 2075 TF; halves instruction
// count per phase). Cycle model: per-K-tile wall = 7014 cyc ~ additive
// {MFMA 2483 + LDS-read 2259 + LDS-write 750 + HBM 860 + sync}; 9 schedule
// variants failed to overlap components, so shrink the MFMA component instead.
// Fragment layouts (guide-verified m74/m101): C/D col=lane&31,
// row=(reg&3)+8*(reg>>2)+4*(lane>>5); A/B operand row=lane&31, k-slot
// ks*2+(lane>>5). Same XOR swizzle both sides (bank touch stays uniform 8/bank).
// Everything else byte-identical to R13.

#define NE   8
#define MAXM 2048
#define KD   2048
#define ND   8192

#define BM   256
#define BN   256
#define BK   64
#define NTS  (KD/BK)     // 32 K-tiles per output tile

typedef __attribute__((ext_vector_type(8)))  short          short8;
typedef __attribute__((ext_vector_type(8)))  unsigned short us8;
typedef __attribute__((ext_vector_type(4)))  float          f32x4;
typedef __attribute__((ext_vector_type(16))) float          f32x16;
typedef __attribute__((ext_vector_type(4)))  unsigned short us4;

__device__ __forceinline__ unsigned short f2bf(float f) {
    union { float f; unsigned u; } v; v.f = f;
    unsigned u = v.u;
    return (unsigned short)((u + 0x7FFFu + ((u >> 16) & 1u)) >> 16);  // RNE
}

__device__ __forceinline__ void gload16(const void* g, void* l) {
    __builtin_amdgcn_global_load_lds(
        (const __attribute__((address_space(1))) void*)g,
        (__attribute__((address_space(3))) void*)l, 16, 0, 0);
}

// ---------------- Pass 1: merged fp32->bf16 conversion (X masked rows skipped) ------
__global__ __launch_bounds__(256) void cvt_all_kernel(const float* __restrict__ x,
                                                      const float* __restrict__ w,
                                                      unsigned short* __restrict__ xb,
                                                      unsigned short* __restrict__ wb,
                                                      const int* __restrict__ ms) {
    int b = blockIdx.x;
    int t = threadIdx.x;
    if (b < NE * MAXM) {
        int e = b >> 11, m = b & 2047;
        if (m >= ms[e]) return;
        const float* s = x + ((size_t)e * MAXM + m) * KD;
        unsigned short* d = xb + ((size_t)e * MAXM + m) * KD;
        const f32x4* s4 = (const f32x4*)(s + t * 8);
        f32x4 a = s4[0], bb = s4[1];
        us8 v = (us8){f2bf(a[0]), f2bf(a[1]), f2bf(a[2]), f2bf(a[3]),
                      f2bf(bb[0]), f2bf(bb[1]), f2bf(bb[2]), f2bf(bb[3])};
        *(us8*)(d + t * 8) = v;
    } else {
        const int nW8 = (int)(((size_t)NE * ND * KD) / 8);   // 16,777,216
        int i = (b - NE * MAXM) * 256 + t;
        int stride = 2048 * 256;
        for (; i < nW8; i += stride) {
            const f32x4* s = (const f32x4*)(w + (size_t)i * 8);
            f32x4 a = s[0], bb = s[1];
            us8 v = (us8){f2bf(a[0]), f2bf(a[1]), f2bf(a[2]), f2bf(a[3]),
                          f2bf(bb[0]), f2bf(bb[1]), f2bf(bb[2]), f2bf(bb[3])};
            *(us8*)(wb + (size_t)i * 8) = v;
        }
    }
}

// ---------------- Pass 2: persistent 2-phase/K-tile 256x256 GEMM (32x32 MFMA) -------
// LDS: A[buf][kh] 256x32 bf16 (16KB) x4 = 64KB; B same = 64KB. Total 128KB.
// LDS[r][slot s] holds global 16B-slot s ^ ((r>>1)&3) (write side: pre-swizzled
// global source ss on lane-linear gload_lds dest). Reads XOR the same term.
// Per K-tile t (buf b), 2 phases (kh = 0,1), each: {12 ds_read | stage 4 | BAR |
// setprio 16x mfma_32x32x16 setprio | vmcnt(8|0) | BAR} -- schedule identical
// to R13; only fragment geometry and epilogue layout changed.
__global__ __launch_bounds__(512, 2) void ggemm_pers(
    const unsigned short* __restrict__ xb,  // [E][MAXM][KD] bf16
    const unsigned short* __restrict__ wb,  // [E][ND][KD]  bf16
    const int*   __restrict__ ms,
    float*       __restrict__ out)          // [E][MAXM][ND] fp32
{
    int p   = blockIdx.x;          // 256 blocks, 1 per CU
    int xcd = p & 7;               // HW round-robins consecutive blockIdx over XCDs
    int jj  = p >> 3;              // 0..31 within XCD
    int tid = threadIdx.x;

    __shared__ int s_live[8], s_dead[8], s_cnt[2];
    __shared__ unsigned short Ak[2][2][BM * 32];   // 64 KB
    __shared__ unsigned short Bk[2][2][BN * 32];   // 64 KB

    // Per-XCD work list, expert-major, br-major within expert, 4 local bc columns.
    if (tid == 0) {
        int nl = 0, nd = 0, cumL = 0, cumD = 0, il = jj, id = jj;
        #pragma unroll
        for (int e = 0; e < NE; ++e) {
            int L = (ms[e] + 255) >> 8;            // live br rows, 0..8
            int cntL = L << 2, cntD = (8 - L) << 2;
            while (il < cumL + cntL) { int o = il - cumL; s_live[nl++] = (e << 5) | ((o >> 2) << 2) | (o & 3); il += 32; }
            while (id < cumD + cntD) { int o = id - cumD; s_dead[nd++] = (e << 5) | ((L + (o >> 2)) << 2) | (o & 3); id += 32; }
            cumL += cntL; cumD += cntD;
        }
        s_cnt[0] = nl; s_cnt[1] = nd;
    }
    __syncthreads();

    // zero-fill dead tiles
    int ndead = s_cnt[1];
    #pragma unroll 1
    for (int d = 0; d < ndead; ++d) {
        int v = s_dead[d]; int e = v >> 5, br = (v >> 2) & 7, bcl = v & 3;
        float* outE = out + (size_t)e * MAXM * ND;
        int row0 = br * BM, col0 = (xcd * 4 + bcl) * BN;
        f32x4 z = (f32x4){0.f, 0.f, 0.f, 0.f};
        #pragma unroll
        for (int q = 0; q < 32; ++q) {
            int i2 = tid + q * 512;
            int rr = i2 >> 6, cc = (i2 & 63) << 2;
            *(f32x4*)(outE + (size_t)(row0 + rr) * ND + col0 + cc) = z;
        }
    }
    int nlive = s_cnt[0];
    if (nlive == 0) return;

    int wid = tid >> 6, lane = tid & 63;
    int wr = wid >> 2, wc = wid & 3;            // 2x4 wave grid; wave owns 128x64
    int r31 = lane & 31, lhi = lane >> 5;       // 32x32 fragment indices
    int rsw = (r31 >> 1) & 3;                   // read-side swizzle term
    int srow = lane >> 2;
    int ss   = (lane & 3) ^ ((lane >> 3) & 3);  // pre-swizzled source slot (involution)

    auto stageA = [&](int b, int kh, const unsigned short* xP, int kt) {
        #pragma unroll
        for (int q = 0; q < 2; ++q) {
            int blk = wid * 2 + q;
            const unsigned short* src =
                xP + (size_t)(blk * 16 + srow) * KD + kt * BK + kh * 32 + ss * 8;
            gload16(src, (char*)&Ak[b][kh][0] + blk * 1024);
        }
    };
    auto stageB = [&](int b, int kh, const unsigned short* wP, int kt) {
        #pragma unroll
        for (int q = 0; q < 2; ++q) {
            int blk = wid * 2 + q;
            const unsigned short* src =
                wP + (size_t)(blk * 16 + srow) * KD + kt * BK + kh * 32 + ss * 8;
            gload16(src, (char*)&Bk[b][kh][0] + blk * 1024);
        }
    };
    // A fragments: a[mc][ks] covers rows wr*128+mc*32+(lane&31), k = kh*32+ks*16+lhi*8
    auto ldA32 = [&](short8 a[4][2], int b, int kh) {
        #pragma unroll
        for (int mc = 0; mc < 4; ++mc)
            #pragma unroll
            for (int ks = 0; ks < 2; ++ks) {
                int row  = wr * 128 + mc * 32 + r31;
                int slot = (ks * 2 + lhi) ^ rsw;
                a[mc][ks] = *(const short8*)&Ak[b][kh][row * 32 + slot * 8];
            }
    };
    auto ldB32 = [&](short8 bf[2][2], int b, int kh) {
        #pragma unroll
        for (int nc = 0; nc < 2; ++nc)
            #pragma unroll
            for (int ks = 0; ks < 2; ++ks) {
                int row  = wc * 64 + nc * 32 + r31;
                int slot = (ks * 2 + lhi) ^ rsw;
                bf[nc][ks] = *(const short8*)&Bk[b][kh][row * 32 + slot * 8];
            }
    };

    f32x16 acc[4][2];
    #pragma unroll
    for (int mc = 0; mc < 4; ++mc)
        #pragma unroll
        for (int nc = 0; nc < 2; ++nc)
            acc[mc][nc] = (f32x16)(0.f);

    // slot metadata (cur / next)
    const unsigned short *xC, *wC, *xN, *wN;
    float *oC, *oN;
    int msC, r0C, c0C, msN, r0N, c0N;
    {
        int v = s_live[0]; int e = v >> 5, br = (v >> 2) & 7, bcl = v & 3;
        r0C = br * BM; c0C = (xcd * 4 + bcl) * BN; msC = ms[e];
        xC = xb + ((size_t)e * MAXM + r0C) * KD;
        wC = wb + ((size_t)e * ND + c0C) * KD;
        oC = out + (size_t)e * MAXM * ND;
    }
    if (nlive > 1) {
        int v = s_live[1]; int e = v >> 5, br = (v >> 2) & 7, bcl = v & 3;
        r0N = br * BM; c0N = (xcd * 4 + bcl) * BN; msN = ms[e];
        xN = xb + ((size_t)e * MAXM + r0N) * KD;
        wN = wb + ((size_t)e * ND + c0N) * KD;
        oN = out + (size_t)e * MAXM * ND;
    } else { xN = xC; wN = wC; oN = oC; msN = msC; r0N = r0C; c0N = c0C; }

    // prologue: kh0(t0)->[0][0], kh1(t0)->[0][1], kh0(t1)->[1][0]; drain kh0(t0)
    stageA(0, 0, xC, 0); stageB(0, 0, wC, 0);
    stageA(0, 1, xC, 0); stageB(0, 1, wC, 0);
    stageA(1, 0, xC, 1); stageB(1, 0, wC, 1);
    asm volatile("s_waitcnt vmcnt(8)" ::: "memory");
    __builtin_amdgcn_s_barrier();

    #pragma unroll 1
    for (int s = 0; s < nlive; ++s) {
        bool last  = (s + 1 >= nlive);
        bool alive = (r0C + wr * 128) < msC;   // wave-uniform dead-half skip

        auto tile = [&](int b, int kt) {
            bool g1 = (kt + 1 < NTS) || (!last);
            bool g2 = (kt + 2 < NTS) || (!last);
            const unsigned short* xS1 = (kt + 1 < NTS) ? xC : xN;
            const unsigned short* wS1 = (kt + 1 < NTS) ? wC : wN;
            int k1 = (kt + 1 < NTS) ? kt + 1 : 0;
            const unsigned short* xS2 = (kt + 2 < NTS) ? xC : xN;
            const unsigned short* wS2 = (kt + 2 < NTS) ? wC : wN;
            int k2 = (kt + 2 < NTS) ? kt + 2 : kt + 2 - NTS;

            short8 a[4][2], bf[2][2];
            // ---- P0: kh0 (full K=32 via 2 ksteps of 16)
            if (alive) { ldA32(a, b, 0); ldB32(bf, b, 0); }
            if (g1) { stageA(b ^ 1, 1, xS1, k1); stageB(b ^ 1, 1, wS1, k1); }
            __builtin_amdgcn_s_barrier();
            __builtin_amdgcn_s_setprio(1);
            if (alive) {
                #pragma unroll
                for (int ks = 0; ks < 2; ++ks)
                    #pragma unroll
                    for (int mc = 0; mc < 4; ++mc)
                        #pragma unroll
                        for (int nc = 0; nc < 2; ++nc)
                            acc[mc][nc] = __builtin_amdgcn_mfma_f32_32x32x16_bf16(
                                a[mc][ks], bf[nc][ks], acc[mc][nc], 0, 0, 0);
            }
            __builtin_amdgcn_s_setprio(0);
            if (g1) { asm volatile("s_waitcnt vmcnt(8)" ::: "memory"); }
            else    { asm volatile("s_waitcnt vmcnt(0)" ::: "memory"); }
            __builtin_amdgcn_s_barrier();
            // ---- P1: kh1
            if (alive) { ldA32(a, b, 1); ldB32(bf, b, 1); }
            if (g2) { stageA(b, 0, xS2, k2); stageB(b, 0, wS2, k2); }
            __builtin_amdgcn_s_barrier();
            __builtin_amdgcn_s_setprio(1);
            if (alive) {
                #pragma unroll
                for (int ks = 0; ks < 2; ++ks)
                    #pragma unroll
                    for (int mc = 0; mc < 4; ++mc)
                        #pragma unroll
                        for (int nc = 0; nc < 2; ++nc)
                            acc[mc][nc] = __builtin_amdgcn_mfma_f32_32x32x16_bf16(
                                a[mc][ks], bf[nc][ks], acc[mc][nc], 0, 0, 0);
            }
            __builtin_amdgcn_s_setprio(0);
            if (g2) { asm volatile("s_waitcnt vmcnt(8)" ::: "memory"); }
            else    { asm volatile("s_waitcnt vmcnt(0)" ::: "memory"); }
            __builtin_amdgcn_s_barrier();
        };

        #pragma unroll 1
        for (int kt = 0; kt < NTS; kt += 2) {
            tile(0, kt);
            tile(1, kt + 1);
        }

        // epilogue: C/D 32x32 layout: col = lane&31, row = (reg&3)+8*(reg>>2)+4*lhi
        #pragma unroll
        for (int mc = 0; mc < 4; ++mc) {
            int rbase = r0C + wr * 128 + mc * 32 + 4 * lhi;
            #pragma unroll
            for (int nc = 0; nc < 2; ++nc) {
                int gc = c0C + wc * 64 + nc * 32 + r31;
                #pragma unroll
                for (int rg = 0; rg < 16; ++rg) {
                    int gr = rbase + (rg & 3) + 8 * (rg >> 2);
                    float v = (gr < msC) ? acc[mc][nc][rg] : 0.f;
                    oC[(size_t)gr * ND + gc] = v;
                    acc[mc][nc][rg] = 0.f;
                }
            }
        }

        // shift slot window
        xC = xN; wC = wN; oC = oN; msC = msN; r0C = r0N; c0C = c0N;
        if (s + 2 < nlive) {
            int v = s_live[s + 2]; int e = v >> 5, br = (v >> 2) & 7, bcl = v & 3;
            r0N = br * BM; c0N = (xcd * 4 + bcl) * BN; msN = ms[e];
            xN = xb + ((size_t)e * MAXM + r0N) * KD;
            wN = wb + ((size_t)e * ND + c0N) * KD;
            oN = out + (size_t)e * MAXM * ND;
        }
    }
}

// ---------------- Fallback: round-1 fused kernel (used only if ws too small) --------
#define FBM 128
#define FBK 32
#define FTM (MAXM/FBM)
#define FTN (ND/FBM)
#define FNT (KD/FBK)
#define LSTR 40
__global__ __launch_bounds__(256, 2) void ggemm_fused(
    const float* __restrict__ x, const float* __restrict__ w,
    const int* __restrict__ ms, float* __restrict__ out)
{
    int nwg  = gridDim.x;
    int orig = blockIdx.x;
    int cpx  = nwg >> 3;
    int bid  = (orig & 7) * cpx + (orig >> 3);
    int e   = bid / (FTM * FTN);
    int rem = bid % (FTM * FTN);
    int br  = rem % FTM;
    int bc  = rem / FTM;
    int m_size = ms[e];
    int row0 = br * FBM, col0 = bc * FBM;
    float* outE = out + (size_t)e * MAXM * ND;
    int tid = threadIdx.x;

    if (row0 >= m_size) {
        f32x4 z = (f32x4){0.f, 0.f, 0.f, 0.f};
        #pragma unroll
        for (int q = 0; q < 16; ++q) {
            int i2 = tid + q * 256;
            int rr = i2 >> 5, cc = (i2 & 31) << 2;
            *(f32x4*)(outE + (size_t)(row0 + rr) * ND + col0 + cc) = z;
        }
        return;
    }

    const float* xE = x + ((size_t)e * MAXM + row0) * KD;
    const float* wE = w + ((size_t)e * ND   + col0) * KD;

    __shared__ unsigned short As[2][FBM][LSTR];
    __shared__ unsigned short Bs[2][FBM][LSTR];

    int sr  = tid >> 3;
    int sc4 = tid & 7;
    int wid = tid >> 6, lane = tid & 63;
    int wr = wid >> 1, wc = wid & 1;
    int lr = lane & 15, kg = lane >> 4;

    f32x4 acc[4][4];
    #pragma unroll
    for (int m = 0; m < 4; ++m)
        #pragma unroll
        for (int n = 0; n < 4; ++n)
            acc[m][n] = (f32x4){0.f, 0.f, 0.f, 0.f};

    {
        #pragma unroll
        for (int q = 0; q < 4; ++q) {
            int r0 = sr + q * 32;
            f32x4 av = *(const f32x4*)(xE + (size_t)r0 * KD + sc4 * 4);
            f32x4 bv = *(const f32x4*)(wE + (size_t)r0 * KD + sc4 * 4);
            us4 ah = (us4){f2bf(av[0]), f2bf(av[1]), f2bf(av[2]), f2bf(av[3])};
            us4 bh = (us4){f2bf(bv[0]), f2bf(bv[1]), f2bf(bv[2]), f2bf(bv[3])};
            *(us4*)&As[0][r0][sc4 * 4] = ah;
            *(us4*)&Bs[0][r0][sc4 * 4] = bh;
        }
    }
    __syncthreads();

    for (int t = 0; t < FNT; ++t) {
        int cur = t & 1;
        f32x4 av[4], bv[4];
        bool pre = (t + 1 < FNT);
        if (pre) {
            const float* xk = xE + (size_t)(t + 1) * FBK;
            const float* wk = wE + (size_t)(t + 1) * FBK;
            #pragma unroll
            for (int q = 0; q < 4; ++q) {
                int r0 = sr + q * 32;
                av[q] = *(const f32x4*)(xk + (size_t)r0 * KD + sc4 * 4);
                bv[q] = *(const f32x4*)(wk + (size_t)r0 * KD + sc4 * 4);
            }
        }
        short8 a[4], b[4];
        #pragma unroll
        for (int m = 0; m < 4; ++m)
            a[m] = *(const short8*)&As[cur][wr * 64 + m * 16 + lr][kg * 8];
        #pragma unroll
        for (int n = 0; n < 4; ++n)
            b[n] = *(const short8*)&Bs[cur][wc * 64 + n * 16 + lr][kg * 8];
        #pragma unroll
        for (int m = 0; m < 4; ++m)
            #pragma unroll
            for (int n = 0; n < 4; ++n)
                acc[m][n] = __builtin_amdgcn_mfma_f32_16x16x32_bf16(a[m], b[n], acc[m][n], 0, 0, 0);

        if (pre) {
            int nb = cur ^ 1;
            #pragma unroll
            for (int q = 0; q < 4; ++q) {
                int r0 = sr + q * 32;
                us4 ah = (us4){f2bf(av[q][0]), f2bf(av[q][1]), f2bf(av[q][2]), f2bf(av[q][3])};
                us4 bh = (us4){f2bf(bv[q][0]), f2bf(bv[q][1]), f2bf(bv[q][2]), f2bf(bv[q][3])};
                *(us4*)&As[nb][r0][sc4 * 4] = ah;
                *(us4*)&Bs[nb][r0][sc4 * 4] = bh;
            }
        }
        __syncthreads();
    }

    #pragma unroll
    for (int m = 0; m < 4; ++m) {
        int rbase = row0 + wr * 64 + m * 16 + kg * 4;
        #pragma unroll
        for (int n = 0; n < 4; ++n) {
            int gc = col0 + wc * 64 + n * 16 + lr;
            #pragma unroll
            for (int q = 0; q < 4; ++q) {
                int gr = rbase + q;
                float v = (gr < m_size) ? acc[m][n][q] : 0.f;
                outE[(size_t)gr * ND + gc] = v;
            }
        }
    }
}

extern "C" void kernel_launch(void* const* d_in, const int* in_sizes, int n_in,
                              void* d_out, int out_size, void* d_ws, size_t ws_size,
                              hipStream_t stream) {
    const float* x  = (const float*)d_in[0];
    const float* w  = (const float*)d_in[1];
    const int*   ms = (const int*)d_in[2];
    float* out = (float*)d_out;

    const size_t xElems = (size_t)NE * MAXM * KD;   // 33,554,432
    const size_t wElems = (size_t)NE * ND   * KD;   // 134,217,728
    const size_t need   = (xElems + wElems) * 2;    // 335,544,320 B

    if (ws_size >= need) {
        unsigned short* xb = (unsigned short*)d_ws;
        unsigned short* wb = xb + xElems;
        cvt_all_kernel<<<NE * MAXM + 2048, 256, 0, stream>>>(x, w, xb, wb, ms);
        ggemm_pers<<<256, 512, 0, stream>>>(xb, wb, ms, out);
    } else {
        ggemm_fused<<<dim3(NE * (MAXM/FBM) * (ND/FBM)), dim3(256), 0, stream>>>(x, w, ms, out);
    }
}